// Round 1
// baseline (235.817 us; speedup 1.0000x reference)
//
#include <hip/hip_runtime.h>

// ForwardTransformLayer: lifting step with circular 8-tap convolutions.
//   even = in[:, ::2], odd = in[:, 1::2]            (row length 8192 -> 4096 each)
//   odd_out[k]  = odd[k]  - sum_j even[(k-j) mod n] * wavelet[j]
//   even_out[k] = even[k] - sum_j odd[(k-j)  mod n] * scaling[j]
//   wavelet[j] = scaling_rec[7-j] * (j odd ? -1 : +1)
// d_out layout: even_out (rows*4096) then odd_out (rows*4096), row-major.
//
// R4 design: R3 was latency/churn-bound, not traffic-bound (3.37 TB/s logical
// vs 6.3 ceiling; VALUBusy 9%, wire 32%, per-wave lifetime ~33k cycles for
// ~1.3k cycles of work). 32768 one-shot waves (load -> wait -> compute ->
// store -> die) never build a steady issue stream; the rocclr fill hits
// 6.7 TB/s at 9% occupancy with long-lived grid-stride waves. Fix:
// grid-stride ITERS=4 with software pipelining -- consume v/h, immediately
// issue next iteration's loads into the same registers, then compute.
// launch_bounds(256,4) gives the compiler a 128-VGPR budget so the pipeline
// isn't collapsed back to the 32-reg serialized schedule R3 compiled to.

#define COLS       8192
#define HALF       4096
#define PAIRS_PT   8                          // pairs (outputs per array) per thread
#define NTHREADS   256
#define CHUNKS_PER_ROW (HALF / PAIRS_PT)      // 512 -> row boundaries align to wave boundaries
#define ITERS      4                          // chunks per thread (grid-stride)

__global__ __launch_bounds__(NTHREADS, 4) void fwd_dwt_kernel(
    const float* __restrict__ input,
    const float* __restrict__ scaling,
    const float* __restrict__ scaling_rec,
    float* __restrict__ out,
    int rows)
{
    const int lane   = threadIdx.x & 63;
    const int stride = gridDim.x * NTHREADS;   // chunk stride per iteration (mult of 512)
    int c = blockIdx.x * NTHREADS + threadIdx.x;

    // Filters (uniform scalar loads -> SGPRs).
    float w[8], sc[8];
#pragma unroll
    for (int j = 0; j < 8; ++j) {
        w[j]  = scaling_rec[7 - j] * ((j & 1) ? -1.0f : 1.0f);
        sc[j] = scaling[j];
    }

    float4 v[4], h[4];

    // Prologue: loads for iteration 0.
    {
        const float* in_row = input + (size_t)(c >> 9) * COLS;
        const int k0 = (c & (CHUNKS_PER_ROW - 1)) * PAIRS_PT;
        const float4* p = (const float4*)(in_row + 2 * k0);
#pragma unroll
        for (int i = 0; i < 4; ++i) v[i] = p[i];
        if (lane == 0) {
            const int hb = (k0 - PAIRS_PT) & (HALF - 1);
            const float4* ph = (const float4*)(in_row + 2 * hb);
#pragma unroll
            for (int i = 0; i < 4; ++i) h[i] = ph[i];
        }
    }

#pragma unroll
    for (int it = 0; it < ITERS; ++it) {
        const int row = c >> 9;
        const int k0  = (c & (CHUNKS_PER_ROW - 1)) * PAIRS_PT;

        // Unpack current payload (consumes v).
        float E[8], O[8];
#pragma unroll
        for (int i = 0; i < 4; ++i) {
            E[2 * i]     = v[i].x;  O[2 * i]     = v[i].y;
            E[2 * i + 1] = v[i].z;  O[2 * i + 1] = v[i].w;
        }

        // Full windows EF/OF[i] = pair (k0-7+i), i = 0..14.
        float EF[15], OF[15];
#pragma unroll
        for (int i = 0; i < 8; ++i) { EF[7 + i] = E[i]; OF[7 + i] = O[i]; }
#pragma unroll
        for (int i = 1; i < 8; ++i) {
            EF[i - 1] = __shfl_up(E[i], 1);
            OF[i - 1] = __shfl_up(O[i], 1);
        }
        // Lane 0: previous chunk from the halo load (consumes h).
        if (lane == 0) {
#pragma unroll
            for (int p = 1; p < 8; ++p) {
                EF[p - 1] = (p & 1) ? h[p / 2].z : h[p / 2].x;
                OF[p - 1] = (p & 1) ? h[p / 2].w : h[p / 2].y;
            }
        }

        // v and h are consumed: issue next iteration's loads NOW so they
        // overlap the 128-FMA block + stores below.
        const int cn = c + stride;
        if (it + 1 < ITERS) {
            const float* in_rowN = input + (size_t)(cn >> 9) * COLS;
            const int k0n = (cn & (CHUNKS_PER_ROW - 1)) * PAIRS_PT;
            const float4* pn = (const float4*)(in_rowN + 2 * k0n);
#pragma unroll
            for (int i = 0; i < 4; ++i) v[i] = pn[i];
            if (lane == 0) {
                const int hbn = (k0n - PAIRS_PT) & (HALF - 1);
                const float4* phn = (const float4*)(in_rowN + 2 * hbn);
#pragma unroll
                for (int i = 0; i < 4; ++i) h[i] = phn[i];
            }
        }

        // even_out[k0+q] = E[q] - sum_j OF[7+q-j]*sc[j]
        // odd_out [k0+q] = O[q] - sum_j EF[7+q-j]*w[j]
        float eo[8], oo[8];
#pragma unroll
        for (int q = 0; q < 8; ++q) {
            float a = 0.0f, b = 0.0f;
#pragma unroll
            for (int j = 0; j < 8; ++j) {
                a += OF[7 + q - j] * sc[j];
                b += EF[7 + q - j] * w[j];
            }
            eo[q] = E[q] - a;
            oo[q] = O[q] - b;
        }

        float* oe = out + (size_t)row * HALF + k0;
        float* od = out + (size_t)rows * HALF + (size_t)row * HALF + k0;

        ((float4*)oe)[0] = make_float4(eo[0], eo[1], eo[2], eo[3]);
        ((float4*)oe)[1] = make_float4(eo[4], eo[5], eo[6], eo[7]);
        ((float4*)od)[0] = make_float4(oo[0], oo[1], oo[2], oo[3]);
        ((float4*)od)[1] = make_float4(oo[4], oo[5], oo[6], oo[7]);

        c = cn;
    }
}

extern "C" void kernel_launch(void* const* d_in, const int* in_sizes, int n_in,
                              void* d_out, int out_size, void* d_ws, size_t ws_size,
                              hipStream_t stream) {
    const float* input       = (const float*)d_in[0];
    const float* scaling     = (const float*)d_in[1];
    const float* scaling_rec = (const float*)d_in[2];
    float*       out         = (float*)d_out;

    const int rows   = in_sizes[0] / COLS;                          // 4096
    const int chunks = rows * CHUNKS_PER_ROW;                       // 2,097,152
    const int blocks = chunks / (NTHREADS * ITERS);                 // 2048
    fwd_dwt_kernel<<<blocks, NTHREADS, 0, stream>>>(
        input, scaling, scaling_rec, out, rows);
}